// Round 2
// baseline (753.761 us; speedup 1.0000x reference)
//
#include <hip/hip_runtime.h>

#define NN 50000
#define NE 800000
#define BK 32                       // nodes per bucket
#define NB ((NN + BK - 1) / BK)     // 1563 buckets
#define MAXB 1024                   // mean 512, std ~23 -> 1024 = +22 sigma, safe

typedef __attribute__((ext_vector_type(8))) short bf16x8;
typedef __attribute__((ext_vector_type(8))) unsigned short us8;
typedef __attribute__((ext_vector_type(4))) unsigned short us4;
typedef __attribute__((ext_vector_type(4))) float f32x4;

#define MFMA16 __builtin_amdgcn_mfma_f32_16x16x32_bf16

__device__ __forceinline__ unsigned short f2b(float f) {
    union { float f; unsigned int u; } x; x.f = f;
    unsigned int r = x.u + 0x7FFFu + ((x.u >> 16) & 1u);
    return (unsigned short)(r >> 16);
}

// ---------------- prep: convert nodes to bf16; convert+transpose weights ----------------
__global__ __launch_bounds__(256) void prep_kernel(
    const float* __restrict__ nodes,
    const float* __restrict__ We1, const float* __restrict__ We2,
    const float* __restrict__ Wn1, const float* __restrict__ Wn2,
    unsigned short* __restrict__ nodes_bf,
    unsigned short* __restrict__ We1T, unsigned short* __restrict__ We2T,
    unsigned short* __restrict__ Wn1T, unsigned short* __restrict__ Wn2T)
{
    const int b = blockIdx.x, t = threadIdx.x;
    if (b < 400) {
        const float4* src = (const float4*)nodes;
        for (int i = b * 256 + t; i < NN * 16; i += 400 * 256) {
            float4 v = src[i];
            us4 o; o[0] = f2b(v.x); o[1] = f2b(v.y); o[2] = f2b(v.z); o[3] = f2b(v.w);
            *(us4*)&nodes_bf[(size_t)i * 4] = o;
        }
    } else {
        const int base = (b - 400) * 256 + t;
        for (int idx = base; idx < 57344; idx += 16 * 256) {
            if (idx < 24576) {               // We1T[128][192] <- We1[192][128]
                int n = idx / 192, k = idx % 192;
                We1T[idx] = f2b(We1[k * 128 + n]);
            } else if (idx < 32768) {        // We2T[64][128] <- We2[128][64]
                int j = idx - 24576; int n = j / 128, k = j % 128;
                We2T[j] = f2b(We2[k * 64 + n]);
            } else if (idx < 49152) {        // Wn1T[128][128] <- Wn1[128][128]
                int j = idx - 32768; int n = j / 128, k = j % 128;
                Wn1T[j] = f2b(Wn1[k * 128 + n]);
            } else {                         // Wn2T[64][128] <- Wn2[128][64]
                int j = idx - 49152; int n = j / 128, k = j % 128;
                Wn2T[j] = f2b(Wn2[k * 64 + n]);
            }
        }
    }
}

// ---------------- build: bucket edges by receiver window (32 nodes/bucket) ----------------
__global__ __launch_bounds__(256) void build_kernel(
    const int* __restrict__ receivers, int* __restrict__ gcnt, int* __restrict__ blist)
{
    int e = blockIdx.x * 256 + threadIdx.x;
    if (e < NE) {
        int r = receivers[e];
        int b = r >> 5;
        int pos = atomicAdd(&gcnt[b], 1);
        if (pos < MAXB) blist[(size_t)b * MAXB + pos] = (e << 5) | (r & 31);
    }
}

// ---------------- edge kernel: one block per bucket; LDS aggregation; zero global atomics ----
__global__ __launch_bounds__(256, 3) void edge_kernel(
    const unsigned short* __restrict__ nodes_bf, const float* __restrict__ edges,
    const unsigned short* __restrict__ We1T, const float* __restrict__ be1,
    const unsigned short* __restrict__ We2T, const float* __restrict__ be2,
    const int* __restrict__ senders, const int* __restrict__ gcnt,
    const int* __restrict__ blist, float* __restrict__ agg)
{
    __shared__ unsigned short xs[64 * 200];   // 25.6 KB; hs aliases with stride 136
    __shared__ float aggs[BK * 66];           // 8.25 KB f32 accumulator, stride 66
    __shared__ int eidx[64];
    __shared__ int lrid[64];
    __shared__ int sidx[64];

    const int t = threadIdx.x;
    const int b = blockIdx.x;
    const int n0 = b * BK;
    const int w = t >> 6;        // wave 0..3
    const int l = t & 63;
    const int lc = l & 15;       // lane col
    const int lq = l >> 4;       // quad

    for (int i = t; i < BK * 66; i += 256) aggs[i] = 0.f;

    // hoist all weights into registers (once per block): 16 x bf16x8 = 64 VGPRs
    bf16x8 wA0[6], wA1[6], wB[4];
    #pragma unroll
    for (int c = 0; c < 6; ++c) {
        wA0[c] = *(const bf16x8*)&We1T[(w * 32 + lc) * 192 + c * 32 + lq * 8];
        wA1[c] = *(const bf16x8*)&We1T[(w * 32 + 16 + lc) * 192 + c * 32 + lq * 8];
    }
    #pragma unroll
    for (int c = 0; c < 4; ++c)
        wB[c] = *(const bf16x8*)&We2T[(w * 16 + lc) * 128 + c * 32 + lq * 8];

    const float b1x = be1[w * 32 + lc];
    const float b1y = be1[w * 32 + 16 + lc];
    const float bias2 = be2[w * 16 + lc];

    int cnt = gcnt[b]; if (cnt > MAXB) cnt = MAXB;
    const int nt = (cnt + 63) >> 6;

    for (int tile = 0; tile < nt; ++tile) {
        const int i0 = tile * 64;
        __syncthreads();                       // prev tile's xs reads + list arrays done
        if (t < 64) {
            int i = i0 + t;
            int e = 0, lr = -1;
            if (i < cnt) { int pk = blist[(size_t)b * MAXB + i]; e = pk >> 5; lr = pk & 31; }
            eidx[t] = e; lrid[t] = lr; sidx[t] = senders[e];
        }
        __syncthreads();

        // stage edges (fp32 -> bf16), gathered 256B rows
        #pragma unroll
        for (int i = 0; i < 4; ++i) {
            int idx = t + 256 * i;
            int m = idx >> 4, q = idx & 15;
            float4 v = *(const float4*)&edges[(size_t)eidx[m] * 64 + q * 4];
            us4 o; o[0] = f2b(v.x); o[1] = f2b(v.y); o[2] = f2b(v.z); o[3] = f2b(v.w);
            *(us4*)&xs[m * 200 + q * 4] = o;
        }
        // receiver feats: from the block's 32-node window (L2-hot)
        #pragma unroll
        for (int i = 0; i < 2; ++i) {
            int idx = t + 256 * i;
            int m = idx >> 3, q = idx & 7;
            int lr = lrid[m];
            int rn = n0 + (lr < 0 ? 0 : lr);
            us8 v = *(const us8*)&nodes_bf[(size_t)rn * 64 + q * 8];
            *(us8*)&xs[m * 200 + 64 + q * 8] = v;
        }
        // sender feats (gathered)
        #pragma unroll
        for (int i = 0; i < 2; ++i) {
            int idx = t + 256 * i;
            int m = idx >> 3, q = idx & 7;
            us8 v = *(const us8*)&nodes_bf[(size_t)sidx[m] * 64 + q * 8];
            *(us8*)&xs[m * 200 + 128 + q * 8] = v;
        }
        __syncthreads();

        // GEMM1: [64,192] @ We1[192,128], register weights, no inner barriers
        f32x4 acc[4][2];
        #pragma unroll
        for (int mt = 0; mt < 4; ++mt) { acc[mt][0] = (f32x4)0.f; acc[mt][1] = (f32x4)0.f; }
        #pragma unroll
        for (int c = 0; c < 6; ++c) {
            #pragma unroll
            for (int mt = 0; mt < 4; ++mt) {
                bf16x8 a = *(const bf16x8*)&xs[(mt * 16 + lc) * 200 + c * 32 + lq * 8];
                acc[mt][0] = MFMA16(a, wA0[c], acc[mt][0], 0, 0, 0);
                acc[mt][1] = MFMA16(a, wA1[c], acc[mt][1], 0, 0, 0);
            }
        }
        __syncthreads();                       // GEMM1 xs reads done before hs overwrite

        // bias + relu -> hs (aliases xs, stride 136)
        #pragma unroll
        for (int nt2 = 0; nt2 < 2; ++nt2) {
            int col = w * 32 + nt2 * 16 + lc;
            float bias = nt2 ? b1y : b1x;
            #pragma unroll
            for (int mt = 0; mt < 4; ++mt) {
                #pragma unroll
                for (int r = 0; r < 4; ++r) {
                    int row = mt * 16 + lq * 4 + r;
                    float v = fmaxf(acc[mt][nt2][r] + bias, 0.f);
                    xs[row * 136 + col] = f2b(v);
                }
            }
        }
        __syncthreads();

        // GEMM2: [64,128] @ We2[128,64], register weights
        f32x4 acc2[4];
        #pragma unroll
        for (int mt = 0; mt < 4; ++mt) acc2[mt] = (f32x4)0.f;
        #pragma unroll
        for (int c = 0; c < 4; ++c) {
            #pragma unroll
            for (int mt = 0; mt < 4; ++mt) {
                bf16x8 a = *(const bf16x8*)&xs[(mt * 16 + lc) * 136 + c * 32 + lq * 8];
                acc2[mt] = MFMA16(a, wB[c], acc2[mt], 0, 0, 0);
            }
        }

        // accumulate into LDS f32 (ds_add_f32) — no global atomics
        #pragma unroll
        for (int mt = 0; mt < 4; ++mt) {
            #pragma unroll
            for (int r = 0; r < 4; ++r) {
                int row = mt * 16 + lq * 4 + r;
                int lr = lrid[row];
                if (lr >= 0) atomicAdd(&aggs[lr * 66 + w * 16 + lc], acc2[mt][r] + bias2);
            }
        }
    }

    __syncthreads();
    // exactly-once plain store of this bucket's agg rows
    for (int i = t; i < BK * 64; i += 256) {
        int row = i >> 6, c = i & 63;
        int n = n0 + row;
        if (n < NN) agg[(size_t)n * 64 + c] = aggs[row * 66 + c];
    }
}

// ---------------- node kernel: 64 nodes/block, 4 waves, MFMA (f32 agg input) ----------------
__global__ __launch_bounds__(256, 4) void node_kernel(
    const unsigned short* __restrict__ nodes_bf, const float* __restrict__ agg,
    const unsigned short* __restrict__ Wn1T, const float* __restrict__ bn1,
    const unsigned short* __restrict__ Wn2T, const float* __restrict__ bn2,
    float* __restrict__ out)
{
    __shared__ unsigned short xs[64 * 136];
    __shared__ unsigned short wb[128 * 40];

    const int t = threadIdx.x;
    const int n0 = blockIdx.x * 64;
    const int w = t >> 6;
    const int l = t & 63;
    const int lc = l & 15;
    const int lq = l >> 4;

    // stage agg (fp32 -> bf16), cols 0..63
    #pragma unroll
    for (int i = 0; i < 4; ++i) {
        int idx = t + 256 * i;
        int m = idx >> 4, q = idx & 15;
        int n = n0 + m;
        float4 v = make_float4(0.f, 0.f, 0.f, 0.f);
        if (n < NN) v = *(const float4*)&agg[(size_t)n * 64 + q * 4];
        us4 o; o[0] = f2b(v.x); o[1] = f2b(v.y); o[2] = f2b(v.z); o[3] = f2b(v.w);
        *(us4*)&xs[m * 136 + q * 4] = o;
    }
    // stage node feats (bf16), cols 64..127
    #pragma unroll
    for (int i = 0; i < 2; ++i) {
        int idx = t + 256 * i;
        int m = idx >> 3, q = idx & 7;
        int n = n0 + m;
        us8 v = {0, 0, 0, 0, 0, 0, 0, 0};
        if (n < NN) v = *(const us8*)&nodes_bf[(size_t)n * 64 + q * 8];
        *(us8*)&xs[m * 136 + 64 + q * 8] = v;
    }
    __syncthreads();

    // GEMM1: [64,128] @ Wn1[128,128]
    f32x4 acc[4][2];
    #pragma unroll
    for (int mt = 0; mt < 4; ++mt) { acc[mt][0] = (f32x4)0.f; acc[mt][1] = (f32x4)0.f; }

    for (int c = 0; c < 4; ++c) {
        const int k0 = 32 * c;
        #pragma unroll
        for (int i = 0; i < 2; ++i) {
            int idx = t + 256 * i;
            int n = idx >> 2, cc = idx & 3;
            *(us8*)&wb[n * 40 + cc * 8] = *(const us8*)&Wn1T[n * 128 + k0 + cc * 8];
        }
        __syncthreads();
        bf16x8 b0 = *(const bf16x8*)&wb[(w * 32 + lc) * 40 + lq * 8];
        bf16x8 b1 = *(const bf16x8*)&wb[(w * 32 + 16 + lc) * 40 + lq * 8];
        #pragma unroll
        for (int mt = 0; mt < 4; ++mt) {
            bf16x8 a = *(const bf16x8*)&xs[(mt * 16 + lc) * 136 + k0 + lq * 8];
            acc[mt][0] = MFMA16(a, b0, acc[mt][0], 0, 0, 0);
            acc[mt][1] = MFMA16(a, b1, acc[mt][1], 0, 0, 0);
        }
        __syncthreads();
    }

    // bias + relu -> hs (same region, stride 136)
    #pragma unroll
    for (int nt = 0; nt < 2; ++nt) {
        int col = w * 32 + nt * 16 + lc;
        float bias = bn1[col];
        #pragma unroll
        for (int mt = 0; mt < 4; ++mt) {
            #pragma unroll
            for (int r = 0; r < 4; ++r) {
                int row = mt * 16 + lq * 4 + r;
                float v = fmaxf(acc[mt][nt][r] + bias, 0.f);
                xs[row * 136 + col] = f2b(v);
            }
        }
    }
    __syncthreads();

    // GEMM2: [64,128] @ Wn2[128,64]
    f32x4 acc2[4];
    #pragma unroll
    for (int mt = 0; mt < 4; ++mt) acc2[mt] = (f32x4)0.f;

    for (int c = 0; c < 4; ++c) {
        const int k0 = 32 * c;
        {
            int n = t >> 2, cc = t & 3;
            *(us8*)&wb[n * 40 + cc * 8] = *(const us8*)&Wn2T[n * 128 + k0 + cc * 8];
        }
        __syncthreads();
        bf16x8 b = *(const bf16x8*)&wb[(w * 16 + lc) * 40 + lq * 8];
        #pragma unroll
        for (int mt = 0; mt < 4; ++mt) {
            bf16x8 a = *(const bf16x8*)&xs[(mt * 16 + lc) * 136 + k0 + lq * 8];
            acc2[mt] = MFMA16(a, b, acc2[mt], 0, 0, 0);
        }
        __syncthreads();
    }

    const int col = w * 16 + lc;
    const float bias2 = bn2[col];
    #pragma unroll
    for (int mt = 0; mt < 4; ++mt) {
        #pragma unroll
        for (int r = 0; r < 4; ++r) {
            int row = mt * 16 + lq * 4 + r;
            int n = n0 + row;
            if (n < NN) out[(size_t)n * 64 + col] = acc2[mt][r] + bias2;
        }
    }
}

extern "C" void kernel_launch(void* const* d_in, const int* in_sizes, int n_in,
                              void* d_out, int out_size, void* d_ws, size_t ws_size,
                              hipStream_t stream) {
    const float* nodes = (const float*)d_in[0];
    const float* edges = (const float*)d_in[1];
    const float* We1   = (const float*)d_in[2];
    const float* be1   = (const float*)d_in[3];
    const float* We2   = (const float*)d_in[4];
    const float* be2   = (const float*)d_in[5];
    const float* Wn1   = (const float*)d_in[6];
    const float* bn1   = (const float*)d_in[7];
    const float* Wn2   = (const float*)d_in[8];
    const float* bn2   = (const float*)d_in[9];
    const int* senders   = (const int*)d_in[10];
    const int* receivers = (const int*)d_in[11];
    float* out = (float*)d_out;

    // ws layout (bytes)
    char* ws = (char*)d_ws;
    float* agg = (float*)ws;                                     // 12,800,000 B
    unsigned short* nodes_bf = (unsigned short*)(ws + 12800000); //  6,400,000 B
    unsigned short* We1T = (unsigned short*)(ws + 19200000);     //     49,152 B
    unsigned short* We2T = (unsigned short*)(ws + 19249152);     //     16,384 B
    unsigned short* Wn1T = (unsigned short*)(ws + 19265536);     //     32,768 B
    unsigned short* Wn2T = (unsigned short*)(ws + 19298304);     //     16,384 B
    int* blist = (int*)(ws + 19314688);                          //  6,402,048 B (NB*MAXB*4)
    int* gcnt  = (int*)(ws + 25716736);                          //      6,252 B

    hipMemsetAsync(gcnt, 0, NB * sizeof(int), stream);
    prep_kernel<<<416, 256, 0, stream>>>(nodes, We1, We2, Wn1, Wn2,
                                         nodes_bf, We1T, We2T, Wn1T, Wn2T);
    build_kernel<<<(NE + 255) / 256, 256, 0, stream>>>(receivers, gcnt, blist);
    edge_kernel<<<NB, 256, 0, stream>>>(nodes_bf, edges, We1T, be1, We2T, be2,
                                        senders, gcnt, blist, agg);
    node_kernel<<<(NN + 63) / 64, 256, 0, stream>>>(nodes_bf, agg, Wn1T, bn1, Wn2T, bn2, out);
}

// Round 3
// 476.833 us; speedup vs baseline: 1.5808x; 1.5808x over previous
//
#include <hip/hip_runtime.h>

#define NN 50000
#define NE 800000
#define NNP 50176            // 196*256, padded node count for scan
#define SCANB 196

typedef __attribute__((ext_vector_type(8))) short bf16x8;
typedef __attribute__((ext_vector_type(8))) unsigned short us8;
typedef __attribute__((ext_vector_type(4))) unsigned short us4;
typedef __attribute__((ext_vector_type(4))) float f32x4;

#define MFMA16 __builtin_amdgcn_mfma_f32_16x16x32_bf16

__device__ __forceinline__ unsigned short f2b(float f) {
    union { float f; unsigned int u; } x; x.f = f;
    unsigned int r = x.u + 0x7FFFu + ((x.u >> 16) & 1u);
    return (unsigned short)(r >> 16);
}
__device__ __forceinline__ float b2f(unsigned short u) {
    union { unsigned int u; float f; } x; x.u = ((unsigned int)u) << 16;
    return x.f;
}
// packed bf16x2 atomic add (fallback path only)
__device__ __forceinline__ void atomic_pk_add_bf16(unsigned short* addr, unsigned int pk) {
    asm volatile("global_atomic_pk_add_bf16 %0, %1, off" :: "v"(addr), "v"(pk) : "memory");
}

// ---------------- prep: convert nodes to bf16; convert+transpose weights ----------------
__global__ __launch_bounds__(256) void prep_kernel(
    const float* __restrict__ nodes,
    const float* __restrict__ We1, const float* __restrict__ We2,
    const float* __restrict__ Wn1, const float* __restrict__ Wn2,
    unsigned short* __restrict__ nodes_bf,
    unsigned short* __restrict__ We1T, unsigned short* __restrict__ We2T,
    unsigned short* __restrict__ Wn1T, unsigned short* __restrict__ Wn2T)
{
    const int b = blockIdx.x, t = threadIdx.x;
    if (b < 400) {
        const float4* src = (const float4*)nodes;
        for (int i = b * 256 + t; i < NN * 16; i += 400 * 256) {
            float4 v = src[i];
            us4 o; o[0] = f2b(v.x); o[1] = f2b(v.y); o[2] = f2b(v.z); o[3] = f2b(v.w);
            *(us4*)&nodes_bf[(size_t)i * 4] = o;
        }
    } else {
        const int base = (b - 400) * 256 + t;
        for (int idx = base; idx < 57344; idx += 16 * 256) {
            if (idx < 24576) {               // We1T[128][192] <- We1[192][128]
                int n = idx / 192, k = idx % 192;
                We1T[idx] = f2b(We1[k * 128 + n]);
            } else if (idx < 32768) {        // We2T[64][128] <- We2[128][64]
                int j = idx - 24576; int n = j / 128, k = j % 128;
                We2T[j] = f2b(We2[k * 64 + n]);
            } else if (idx < 49152) {        // Wn1T[128][128] <- Wn1[128][128]
                int j = idx - 32768; int n = j / 128, k = j % 128;
                Wn1T[j] = f2b(Wn1[k * 128 + n]);
            } else {                         // Wn2T[64][128] <- Wn2[128][64]
                int j = idx - 49152; int n = j / 128, k = j % 128;
                Wn2T[j] = f2b(Wn2[k * 64 + n]);
            }
        }
    }
}

// ---------------- CSR build: histogram + 3-kernel exclusive scan ----------------
__global__ __launch_bounds__(256) void hist_kernel(
    const int* __restrict__ receivers, int* __restrict__ deg)
{
    int e = blockIdx.x * 256 + threadIdx.x;
    if (e < NE) atomicAdd(&deg[receivers[e]], 1);
}

__global__ __launch_bounds__(256) void scan1_kernel(
    const int* __restrict__ deg, int* __restrict__ psum)
{
    __shared__ int red[256];
    int t = threadIdx.x;
    red[t] = deg[blockIdx.x * 256 + t];
    __syncthreads();
    for (int s = 128; s > 0; s >>= 1) {
        if (t < s) red[t] += red[t + s];
        __syncthreads();
    }
    if (t == 0) psum[blockIdx.x] = red[0];
}

__global__ __launch_bounds__(256) void scan2_kernel(
    const int* __restrict__ psum, int* __restrict__ poff)
{
    __shared__ int a[256];
    int t = threadIdx.x;
    int v0 = (t < SCANB) ? psum[t] : 0;
    a[t] = v0;
    __syncthreads();
    for (int off = 1; off < 256; off <<= 1) {
        int x = a[t];
        if (t >= off) x += a[t - off];
        __syncthreads();
        a[t] = x;
        __syncthreads();
    }
    poff[t] = a[t] - v0;   // exclusive
}

__global__ __launch_bounds__(256) void scan3_kernel(
    const int* __restrict__ deg, const int* __restrict__ poff, int* __restrict__ basep)
{
    __shared__ int a[256];
    int t = threadIdx.x, i = blockIdx.x * 256 + t;
    int v0 = deg[i];
    a[t] = v0;
    __syncthreads();
    for (int off = 1; off < 256; off <<= 1) {
        int x = a[t];
        if (t >= off) x += a[t - off];
        __syncthreads();
        a[t] = x;
        __syncthreads();
    }
    basep[i] = poff[blockIdx.x] + a[t] - v0;   // global exclusive scan
}

// ---------------- edge kernel: 64 seq edges/block, reg weights ----------------
// MODE 0: plain scatter-store rows into sorted_e[pos] (CSR). MODE 1: pk-bf16 atomics (fallback).
template<int MODE>
__global__ __launch_bounds__(256, 4) void edge_kernel_t(
    const unsigned short* __restrict__ nodes_bf, const float* __restrict__ edges,
    const unsigned short* __restrict__ We1T, const float* __restrict__ be1,
    const unsigned short* __restrict__ We2T, const float* __restrict__ be2,
    const int* __restrict__ senders, const int* __restrict__ receivers,
    const int* __restrict__ basep, int* __restrict__ cursor,
    unsigned short* __restrict__ sorted_e, unsigned short* __restrict__ agg_bf)
{
    __shared__ __align__(16) unsigned short xs[64 * 200];   // 25.6 KB; hs stride 136; fs stride 68 f32
    __shared__ int ridx[64];
    __shared__ int sidx[64];
    __shared__ int wpos[64];

    const int t = threadIdx.x;
    const int e0 = blockIdx.x * 64;
    const int w = t >> 6, l = t & 63, lc = l & 15, lq = l >> 4;

    int myr = -1;
    if (t < 64) {
        myr = receivers[e0 + t];
        ridx[t] = myr;
        sidx[t] = senders[e0 + t];
    }

    // weights to registers (L2-hot after first blocks): 16 frags = 64 VGPR
    bf16x8 wA0[6], wA1[6], wB[4];
    #pragma unroll
    for (int c = 0; c < 6; ++c) {
        wA0[c] = *(const bf16x8*)&We1T[(w * 32 + lc) * 192 + c * 32 + lq * 8];
        wA1[c] = *(const bf16x8*)&We1T[(w * 32 + 16 + lc) * 192 + c * 32 + lq * 8];
    }
    #pragma unroll
    for (int c = 0; c < 4; ++c)
        wB[c] = *(const bf16x8*)&We2T[(w * 16 + lc) * 128 + c * 32 + lq * 8];
    const float b1x = be1[w * 32 + lc];
    const float b1y = be1[w * 32 + 16 + lc];
    const float bias2 = be2[w * 16 + lc];

    __syncthreads();   // ridx/sidx visible

    // stage edges (fp32 -> bf16), sequential = coalesced streaming
    #pragma unroll
    for (int i = 0; i < 4; ++i) {
        int idx = t + 256 * i;
        int m = idx >> 4, q = idx & 15;
        float4 v = *(const float4*)&edges[((size_t)(e0 + m)) * 64 + q * 4];
        us4 o; o[0] = f2b(v.x); o[1] = f2b(v.y); o[2] = f2b(v.z); o[3] = f2b(v.w);
        *(us4*)&xs[m * 200 + q * 4] = o;
    }
    // gather receiver node feats
    #pragma unroll
    for (int i = 0; i < 2; ++i) {
        int idx = t + 256 * i;
        int m = idx >> 3, q = idx & 7;
        us8 v = *(const us8*)&nodes_bf[(size_t)ridx[m] * 64 + q * 8];
        *(us8*)&xs[m * 200 + 64 + q * 8] = v;
    }
    // gather sender node feats
    #pragma unroll
    for (int i = 0; i < 2; ++i) {
        int idx = t + 256 * i;
        int m = idx >> 3, q = idx & 7;
        us8 v = *(const us8*)&nodes_bf[(size_t)sidx[m] * 64 + q * 8];
        *(us8*)&xs[m * 200 + 128 + q * 8] = v;
    }
    // CSR slot reservation: 1 int atomic per edge, latency hides under staging barrier
    if (MODE == 0 && t < 64) wpos[t] = basep[myr] + atomicAdd(&cursor[myr], 1);
    __syncthreads();

    // GEMM1: [64,192] @ We1[192,128], register weights, no inner barriers
    f32x4 acc[4][2];
    #pragma unroll
    for (int mt = 0; mt < 4; ++mt) { acc[mt][0] = (f32x4)0.f; acc[mt][1] = (f32x4)0.f; }
    #pragma unroll
    for (int c = 0; c < 6; ++c) {
        #pragma unroll
        for (int mt = 0; mt < 4; ++mt) {
            bf16x8 a = *(const bf16x8*)&xs[(mt * 16 + lc) * 200 + c * 32 + lq * 8];
            acc[mt][0] = MFMA16(a, wA0[c], acc[mt][0], 0, 0, 0);
            acc[mt][1] = MFMA16(a, wA1[c], acc[mt][1], 0, 0, 0);
        }
    }
    __syncthreads();

    // bias + relu -> hs (aliases xs, stride 136)
    #pragma unroll
    for (int nt = 0; nt < 2; ++nt) {
        int col = w * 32 + nt * 16 + lc;
        float bias = nt ? b1y : b1x;
        #pragma unroll
        for (int mt = 0; mt < 4; ++mt) {
            #pragma unroll
            for (int r = 0; r < 4; ++r) {
                int row = mt * 16 + lq * 4 + r;
                float v = fmaxf(acc[mt][nt][r] + bias, 0.f);
                xs[row * 136 + col] = f2b(v);
            }
        }
    }
    __syncthreads();

    // GEMM2: [64,128] @ We2[128,64], register weights
    f32x4 acc2[4];
    #pragma unroll
    for (int mt = 0; mt < 4; ++mt) acc2[mt] = (f32x4)0.f;
    #pragma unroll
    for (int c = 0; c < 4; ++c) {
        #pragma unroll
        for (int mt = 0; mt < 4; ++mt) {
            bf16x8 a = *(const bf16x8*)&xs[(mt * 16 + lc) * 136 + c * 32 + lq * 8];
            acc2[mt] = MFMA16(a, wB[c], acc2[mt], 0, 0, 0);
        }
    }
    __syncthreads();   // xs reads done before fs overwrite

    // stage acc2+bias into LDS f32 [64][68] (stride 68: 16B-aligned rows)
    float* fs = (float*)xs;            // 64*68*4 = 17408 B, fits
    {
        const int col = w * 16 + lc;
        #pragma unroll
        for (int mt = 0; mt < 4; ++mt) {
            #pragma unroll
            for (int r = 0; r < 4; ++r) {
                int row = mt * 16 + lq * 4 + r;
                fs[row * 68 + col] = acc2[mt][r] + bias2;
            }
        }
    }
    __syncthreads();

    if (MODE == 0) {
        // plain scatter stores: 8-lane group writes one 128B row (2 rows/group)
        int g = t >> 3, l8 = t & 7;
        #pragma unroll
        for (int k = 0; k < 2; ++k) {
            int row = g * 2 + k;
            size_t p = (size_t)wpos[row];
            float4 va = *(const float4*)&fs[row * 68 + l8 * 8];
            float4 vb = *(const float4*)&fs[row * 68 + l8 * 8 + 4];
            us8 o;
            o[0] = f2b(va.x); o[1] = f2b(va.y); o[2] = f2b(va.z); o[3] = f2b(va.w);
            o[4] = f2b(vb.x); o[5] = f2b(vb.y); o[6] = f2b(vb.z); o[7] = f2b(vb.w);
            *(us8*)&sorted_e[p * 64 + l8 * 8] = o;
        }
    } else {
        // fallback: packed bf16x2 atomics
        #pragma unroll
        for (int i = 0; i < 8; ++i) {
            int p = t + 256 * i;
            int row = p >> 5, cp = p & 31;
            float2 v = *(const float2*)&fs[row * 68 + cp * 2];
            unsigned int pk = (unsigned int)f2b(v.x) | ((unsigned int)f2b(v.y) << 16);
            atomic_pk_add_bf16(&agg_bf[(size_t)ridx[row] * 64 + cp * 2], pk);
        }
    }
}

// ---------------- node kernel: fused segment-sum (MODE 0) + MLP, reg weights ----------------
template<int MODE>
__global__ __launch_bounds__(256, 4) void node_kernel_t(
    const unsigned short* __restrict__ nodes_bf,
    const unsigned short* __restrict__ src,    // MODE0: sorted_e, MODE1: agg_bf
    const int* __restrict__ basep,
    const unsigned short* __restrict__ Wn1T, const float* __restrict__ bn1,
    const unsigned short* __restrict__ Wn2T, const float* __restrict__ bn2,
    float* __restrict__ out)
{
    __shared__ __align__(16) unsigned short xs[64 * 136];
    __shared__ __align__(16) float aggs[(MODE == 0) ? 64 * 64 : 4];
    __shared__ int nbase[65];

    const int t = threadIdx.x;
    const int n0 = blockIdx.x * 64;
    const int w = t >> 6, l = t & 63, lc = l & 15, lq = l >> 4;

    // weights to registers: 12 frags = 48 VGPR
    bf16x8 wA0[4], wA1[4], wB[4];
    #pragma unroll
    for (int c = 0; c < 4; ++c) {
        wA0[c] = *(const bf16x8*)&Wn1T[(w * 32 + lc) * 128 + c * 32 + lq * 8];
        wA1[c] = *(const bf16x8*)&Wn1T[(w * 32 + 16 + lc) * 128 + c * 32 + lq * 8];
        wB[c]  = *(const bf16x8*)&Wn2T[(w * 16 + lc) * 128 + c * 32 + lq * 8];
    }
    const float b1x = bn1[w * 32 + lc];
    const float b1y = bn1[w * 32 + 16 + lc];
    const float bias2 = bn2[w * 16 + lc];

    if (MODE == 0) {
        if (t < 65) nbase[t] = basep[n0 + t];   // n0+64 <= 50048 < NNP, safe
        __syncthreads();
        // segment-sum: 8-lane group sums 2 nodes' contiguous CSR ranges in f32 regs
        int g = t >> 3, l8 = t & 7;
        #pragma unroll
        for (int k = 0; k < 2; ++k) {
            int ln = 2 * g + k, n = n0 + ln;
            float s0 = 0.f, s1 = 0.f, s2 = 0.f, s3 = 0.f, s4 = 0.f, s5 = 0.f, s6 = 0.f, s7 = 0.f;
            if (n < NN) {
                int js = nbase[ln], je = nbase[ln + 1];
                for (int j = js; j < je; ++j) {
                    us8 v = *(const us8*)&src[(size_t)j * 64 + l8 * 8];
                    s0 += b2f(v[0]); s1 += b2f(v[1]); s2 += b2f(v[2]); s3 += b2f(v[3]);
                    s4 += b2f(v[4]); s5 += b2f(v[5]); s6 += b2f(v[6]); s7 += b2f(v[7]);
                }
            }
            *(float4*)&aggs[ln * 64 + l8 * 8]     = make_float4(s0, s1, s2, s3);
            *(float4*)&aggs[ln * 64 + l8 * 8 + 4] = make_float4(s4, s5, s6, s7);
        }
        __syncthreads();
        // convert aggs -> xs cols 0..63 (bf16)
        #pragma unroll
        for (int i = 0; i < 4; ++i) {
            int idx = t + 256 * i;
            int m = idx >> 4, q = idx & 15;
            float4 v = *(const float4*)&aggs[m * 64 + q * 4];
            us4 o; o[0] = f2b(v.x); o[1] = f2b(v.y); o[2] = f2b(v.z); o[3] = f2b(v.w);
            *(us4*)&xs[m * 136 + q * 4] = o;
        }
    } else {
        // stage agg_bf (bf16 copy), cols 0..63
        #pragma unroll
        for (int i = 0; i < 2; ++i) {
            int idx = t + 256 * i;
            int m = idx >> 3, q = idx & 7;
            int n = n0 + m;
            us8 v = {0, 0, 0, 0, 0, 0, 0, 0};
            if (n < NN) v = *(const us8*)&src[(size_t)n * 64 + q * 8];
            *(us8*)&xs[m * 136 + q * 8] = v;
        }
    }
    // stage node feats (bf16), cols 64..127
    #pragma unroll
    for (int i = 0; i < 2; ++i) {
        int idx = t + 256 * i;
        int m = idx >> 3, q = idx & 7;
        int n = n0 + m;
        us8 v = {0, 0, 0, 0, 0, 0, 0, 0};
        if (n < NN) v = *(const us8*)&nodes_bf[(size_t)n * 64 + q * 8];
        *(us8*)&xs[m * 136 + 64 + q * 8] = v;
    }
    __syncthreads();

    // GEMM1: [64,128] @ Wn1[128,128], register weights
    f32x4 acc[4][2];
    #pragma unroll
    for (int mt = 0; mt < 4; ++mt) { acc[mt][0] = (f32x4)0.f; acc[mt][1] = (f32x4)0.f; }
    #pragma unroll
    for (int c = 0; c < 4; ++c) {
        #pragma unroll
        for (int mt = 0; mt < 4; ++mt) {
            bf16x8 a = *(const bf16x8*)&xs[(mt * 16 + lc) * 136 + c * 32 + lq * 8];
            acc[mt][0] = MFMA16(a, wA0[c], acc[mt][0], 0, 0, 0);
            acc[mt][1] = MFMA16(a, wA1[c], acc[mt][1], 0, 0, 0);
        }
    }
    __syncthreads();

    // bias + relu -> hs
    #pragma unroll
    for (int nt = 0; nt < 2; ++nt) {
        int col = w * 32 + nt * 16 + lc;
        float bias = nt ? b1y : b1x;
        #pragma unroll
        for (int mt = 0; mt < 4; ++mt) {
            #pragma unroll
            for (int r = 0; r < 4; ++r) {
                int row = mt * 16 + lq * 4 + r;
                float v = fmaxf(acc[mt][nt][r] + bias, 0.f);
                xs[row * 136 + col] = f2b(v);
            }
        }
    }
    __syncthreads();

    // GEMM2: [64,128] @ Wn2[128,64], register weights
    f32x4 acc2[4];
    #pragma unroll
    for (int mt = 0; mt < 4; ++mt) acc2[mt] = (f32x4)0.f;
    #pragma unroll
    for (int c = 0; c < 4; ++c) {
        #pragma unroll
        for (int mt = 0; mt < 4; ++mt) {
            bf16x8 a = *(const bf16x8*)&xs[(mt * 16 + lc) * 136 + c * 32 + lq * 8];
            acc2[mt] = MFMA16(a, wB[c], acc2[mt], 0, 0, 0);
        }
    }

    const int col = w * 16 + lc;
    #pragma unroll
    for (int mt = 0; mt < 4; ++mt) {
        #pragma unroll
        for (int r = 0; r < 4; ++r) {
            int row = mt * 16 + lq * 4 + r;
            int n = n0 + row;
            if (n < NN) out[(size_t)n * 64 + col] = acc2[mt][r] + bias2;
        }
    }
}

extern "C" void kernel_launch(void* const* d_in, const int* in_sizes, int n_in,
                              void* d_out, int out_size, void* d_ws, size_t ws_size,
                              hipStream_t stream) {
    const float* nodes = (const float*)d_in[0];
    const float* edges = (const float*)d_in[1];
    const float* We1   = (const float*)d_in[2];
    const float* be1   = (const float*)d_in[3];
    const float* We2   = (const float*)d_in[4];
    const float* be2   = (const float*)d_in[5];
    const float* Wn1   = (const float*)d_in[6];
    const float* bn1   = (const float*)d_in[7];
    const float* Wn2   = (const float*)d_in[8];
    const float* bn2   = (const float*)d_in[9];
    const int* senders   = (const int*)d_in[10];
    const int* receivers = (const int*)d_in[11];
    float* out = (float*)d_out;
    char* ws = (char*)d_ws;

    const size_t NEED = 109518144;   // main-path workspace bytes

    if (ws_size >= NEED) {
        // ---- main path: CSR sort + plain stores, fused segsum+MLP ----
        unsigned short* sorted_e = (unsigned short*)ws;              // 102,400,000
        unsigned short* nodes_bf = (unsigned short*)(ws + 102400000); //  6,400,000
        unsigned short* We1T = (unsigned short*)(ws + 108800000);    //     49,152
        unsigned short* We2T = (unsigned short*)(ws + 108849152);    //     16,384
        unsigned short* Wn1T = (unsigned short*)(ws + 108865536);    //     32,768
        unsigned short* Wn2T = (unsigned short*)(ws + 108898304);    //     16,384
        int* deg    = (int*)(ws + 108914688);                        //    200,704
        int* basep  = (int*)(ws + 109115392);                        //    200,704
        int* cursor = (int*)(ws + 109316096);                        //    200,000
        int* psum   = (int*)(ws + 109516096);                        //      1,024
        int* poff   = (int*)(ws + 109517120);                        //      1,024

        hipMemsetAsync(deg, 0, NNP * sizeof(int), stream);
        hipMemsetAsync(cursor, 0, NN * sizeof(int), stream);
        prep_kernel<<<416, 256, 0, stream>>>(nodes, We1, We2, Wn1, Wn2,
                                             nodes_bf, We1T, We2T, Wn1T, Wn2T);
        hist_kernel<<<(NE + 255) / 256, 256, 0, stream>>>(receivers, deg);
        scan1_kernel<<<SCANB, 256, 0, stream>>>(deg, psum);
        scan2_kernel<<<1, 256, 0, stream>>>(psum, poff);
        scan3_kernel<<<SCANB, 256, 0, stream>>>(deg, poff, basep);
        edge_kernel_t<0><<<NE / 64, 256, 0, stream>>>(
            nodes_bf, edges, We1T, be1, We2T, be2, senders, receivers,
            basep, cursor, sorted_e, (unsigned short*)nullptr);
        node_kernel_t<0><<<(NN + 63) / 64, 256, 0, stream>>>(
            nodes_bf, sorted_e, basep, Wn1T, bn1, Wn2T, bn2, out);
    } else {
        // ---- fallback: round-1 proven pk-bf16 atomic path ----
        unsigned short* agg_bf = (unsigned short*)ws;                 //  6,400,000
        unsigned short* nodes_bf = (unsigned short*)(ws + 12800000);  //  6,400,000
        unsigned short* We1T = (unsigned short*)(ws + 19200000);
        unsigned short* We2T = (unsigned short*)(ws + 19249152);
        unsigned short* Wn1T = (unsigned short*)(ws + 19265536);
        unsigned short* Wn2T = (unsigned short*)(ws + 19298304);

        hipMemsetAsync(agg_bf, 0, (size_t)NN * 64 * sizeof(unsigned short), stream);
        prep_kernel<<<416, 256, 0, stream>>>(nodes, We1, We2, Wn1, Wn2,
                                             nodes_bf, We1T, We2T, Wn1T, Wn2T);
        edge_kernel_t<1><<<NE / 64, 256, 0, stream>>>(
            nodes_bf, edges, We1T, be1, We2T, be2, senders, receivers,
            (const int*)nullptr, (int*)nullptr, (unsigned short*)nullptr, agg_bf);
        node_kernel_t<1><<<(NN + 63) / 64, 256, 0, stream>>>(
            nodes_bf, agg_bf, (const int*)nullptr, Wn1T, bn1, Wn2T, bn2, out);
    }
}